// Round 11
// baseline (178.821 us; speedup 1.0000x reference)
//
#include <hip/hip_runtime.h>

#define Bq 8
#define Cc 64
#define Tt 128
#define Nn 512
#define Hh 32

typedef __attribute__((ext_vector_type(8))) short bf16x8;
typedef __attribute__((ext_vector_type(4))) float f32x4;
typedef __attribute__((ext_vector_type(4))) unsigned int u32x4;

__device__ __forceinline__ unsigned short f2bf(float f) {
  union { float f; unsigned int i; } u; u.f = f;
  unsigned int r = (u.i + 0x7FFFu + ((u.i >> 16) & 1u)) >> 16;
  return (unsigned short)r;
}
__device__ __forceinline__ float bf2f(unsigned short h) {
  union { float f; unsigned int i; } u; u.i = ((unsigned int)h) << 16; return u.f;
}
// HW packed f32->bf16 (RNE): low16 = bf16(lo), high16 = bf16(hi)
__device__ __forceinline__ unsigned int cvt2(float lo, float hi) {
  unsigned int r;
  asm("v_cvt_pk_bf16_f32 %0, %1, %2" : "=v"(r) : "v"(lo), "v"(hi));
  return r;
}
__device__ __forceinline__ float redsum16(float v) {
#pragma unroll
  for (int m = 1; m < 16; m <<= 1) v += __shfl_xor(v, m, 64);
  return v;
}

// ---------------- Pass 1: x[B,C,T,N] f32 -> xt[B,N,T,C] bf16 (tiled transpose) ----------------
__global__ __launch_bounds__(256) void sta_tin(const float* __restrict__ x,
                                               unsigned short* __restrict__ xt) {
  __shared__ float tile[64][65];
  const int tid = threadIdx.x;
  const int nb = blockIdx.x, t = blockIdx.y, b = blockIdx.z;
  const int n0 = nb * 64;

#pragma unroll
  for (int i = 0; i < 4; ++i) {
    const int c = i * 16 + (tid >> 4);
    const int nf = (tid & 15) * 4;
    const float4 v = *(const float4*)(x + (((size_t)(b * Cc + c) * Tt + t) * Nn + n0 + nf));
    tile[c][nf + 0] = v.x; tile[c][nf + 1] = v.y; tile[c][nf + 2] = v.z; tile[c][nf + 3] = v.w;
  }
  __syncthreads();

  const int np = tid >> 2;
  const int cq = (tid & 3) * 16;
  unsigned int u[8];
#pragma unroll
  for (int k = 0; k < 8; ++k)
    u[k] = cvt2(tile[cq + 2 * k][np], tile[cq + 2 * k + 1][np]);
  unsigned short* dst = xt + (((size_t)(b * Nn + n0 + np) * Tt + t) * Cc + cq);
  u32x4 s0 = { u[0], u[1], u[2], u[3] };
  u32x4 s1 = { u[4], u[5], u[6], u[7] };
  *(u32x4*)(dst) = s0;
  *(u32x4*)(dst + 8) = s1;
}

// ---------------- Pass 3: yt[B,N,T,C] bf16 -> out[B,C,T,N] f32 (tiled transpose) ----------------
__global__ __launch_bounds__(256) void sta_tout(const unsigned short* __restrict__ yt,
                                                float* __restrict__ out) {
  __shared__ float tile[64][65];
  const int tid = threadIdx.x;
  const int nb = blockIdx.x, t = blockIdx.y, b = blockIdx.z;
  const int n0 = nb * 64;

  {
    const int np = tid >> 2;
    const int cq = (tid & 3) * 16;
    const unsigned short* src = yt + (((size_t)(b * Nn + n0 + np) * Tt + t) * Cc + cq);
    const bf16x8 v0 = *(const bf16x8*)(src);
    const bf16x8 v1 = *(const bf16x8*)(src + 8);
#pragma unroll
    for (int j = 0; j < 8; ++j) {
      tile[np][cq + j]     = bf2f((unsigned short)v0[j]);
      tile[np][cq + 8 + j] = bf2f((unsigned short)v1[j]);
    }
  }
  __syncthreads();

  const int c = tid >> 2;
  const int nq = (tid & 3) * 16;
#pragma unroll
  for (int k = 0; k < 4; ++k) {
    float4 w;
    w.x = tile[nq + 4 * k + 0][c];
    w.y = tile[nq + 4 * k + 1][c];
    w.z = tile[nq + 4 * k + 2][c];
    w.w = tile[nq + 4 * k + 3][c];
    *(float4*)(out + (((size_t)(b * Cc + c) * Tt + t) * Nn + n0 + nq + 4 * k)) = w;
  }
}

// ---------------- Pass 2: fused attention on contiguous bf16 tiles (in-place xt -> yt) ----------------
__global__ __launch_bounds__(256, 3) void sta_core(
    unsigned short* __restrict__ xt,
    const float* __restrict__ wq, const float* __restrict__ bq,
    const float* __restrict__ wk, const float* __restrict__ bk,
    const float* __restrict__ wv, const float* __restrict__ bv,
    const float* __restrict__ wg, const float* __restrict__ bg,
    const float* __restrict__ wo, const float* __restrict__ bo,
    const float* __restrict__ gamma, const float* __restrict__ beta)
{
  __shared__ __align__(16) unsigned short xp[Tt * 72];     // xp[t][c]   18,432 B
  __shared__ __align__(16) unsigned short ksm[Tt * 40];    // k[t][h]    10,240 B
  __shared__ __align__(16) unsigned short vT[Hh * 136];    // vT[h][s]    8,704 B
  __shared__ __align__(16) unsigned short stg[4 * 32 * 40];// per-wave   10,240 B
  __shared__ float pb[128];                                // posbias*log2e  512 B

  const int tid  = threadIdx.x;
  const int lane = tid & 63;
  const int w    = tid >> 6;
  const int g    = lane >> 4;
  const int c0   = lane & 15;
  const int R    = w * 32;

  unsigned short* xtile = xt + (size_t)blockIdx.x * (Tt * Cc);

  // ---------------- Phase 0: contiguous 16KB tile -> LDS ----------------
  {
    const int r = tid >> 1;
    const int half = (tid & 1) * 32;
    const unsigned short* src = xtile + (size_t)r * Cc + half;
    bf16x8 v[4];
#pragma unroll
    for (int j = 0; j < 4; ++j) v[j] = *(const bf16x8*)(src + 8 * j);
#pragma unroll
    for (int j = 0; j < 4; ++j) *(bf16x8*)&xp[r * 72 + half + 8 * j] = v[j];
  }

  // position-bias table: pb[d] = exp(-d/128) * log2(e)  (additive exponent, exp2 domain)
  if (tid < 128) pb[tid] = exp2f((float)tid * -0.0112710550069f) * 1.4426950408889634f;

  // QKV weight B-fragments, built in-kernel (R3-proven path; L2-resident scalar loads)
  bf16x8 bwf[3][2][2];      // [q/k/v][ct][kstep]
  float  bias0[3][2];
  {
    const float* ws3[3] = { wq, wk, wv };
    const float* bs3[3] = { bq, bk, bv };
#pragma unroll
    for (int o = 0; o < 3; ++o) {
#pragma unroll
      for (int ct = 0; ct < 2; ++ct) {
        bias0[o][ct] = bs3[o][ct * 16 + c0];
#pragma unroll
        for (int ks2 = 0; ks2 < 2; ++ks2) {
          const float* m = ws3[o] + (ks2 * 32 + 8 * g) * Hh + ct * 16 + c0;
          bf16x8 f;
#pragma unroll
          for (int j = 0; j < 8; ++j) f[j] = (short)f2bf(m[j * Hh]);
          bwf[o][ct][ks2] = f;
        }
      }
    }
  }

  __syncthreads();

  // ---------------- Phase 1: QKV = xp @ {wq,wk,wv} + bias ----------------
  unsigned short* pst = &stg[w * 1280];
  {
    f32x4 acc[3][2][2];
#pragma unroll
    for (int o = 0; o < 3; ++o)
#pragma unroll
      for (int rt = 0; rt < 2; ++rt)
#pragma unroll
        for (int ct = 0; ct < 2; ++ct) {
          f32x4 a; a[0] = bias0[o][ct]; a[1] = bias0[o][ct]; a[2] = bias0[o][ct]; a[3] = bias0[o][ct];
          acc[o][rt][ct] = a;
        }
    bf16x8 af[2][2];
#pragma unroll
    for (int rt = 0; rt < 2; ++rt)
#pragma unroll
      for (int ks2 = 0; ks2 < 2; ++ks2)
        af[rt][ks2] = *(const bf16x8*)&xp[(R + rt * 16 + c0) * 72 + ks2 * 32 + 8 * g];
#pragma unroll
    for (int o = 0; o < 3; ++o)
#pragma unroll
      for (int rt = 0; rt < 2; ++rt)
#pragma unroll
        for (int ct = 0; ct < 2; ++ct)
#pragma unroll
          for (int ks2 = 0; ks2 < 2; ++ks2)
            acc[o][rt][ct] = __builtin_amdgcn_mfma_f32_16x16x32_bf16(af[rt][ks2], bwf[o][ct][ks2], acc[o][rt][ct], 0, 0, 0);

    // scatter D-frags via packed cvt: q -> pst, k -> ksm, v -> vT (transposed)
#pragma unroll
    for (int rt = 0; rt < 2; ++rt)
#pragma unroll
      for (int ct = 0; ct < 2; ++ct) {
        const unsigned int q01 = cvt2(acc[0][rt][ct][0], acc[0][rt][ct][1]);
        const unsigned int q23 = cvt2(acc[0][rt][ct][2], acc[0][rt][ct][3]);
        const unsigned int k01 = cvt2(acc[1][rt][ct][0], acc[1][rt][ct][1]);
        const unsigned int k23 = cvt2(acc[1][rt][ct][2], acc[1][rt][ct][3]);
        const int qb = (rt * 16 + 4 * g) * 40 + ct * 16 + c0;
        pst[qb]       = (unsigned short)q01;
        pst[qb + 40]  = (unsigned short)(q01 >> 16);
        pst[qb + 80]  = (unsigned short)q23;
        pst[qb + 120] = (unsigned short)(q23 >> 16);
        const int kb = (R + rt * 16 + 4 * g) * 40 + ct * 16 + c0;
        ksm[kb]       = (unsigned short)k01;
        ksm[kb + 40]  = (unsigned short)(k01 >> 16);
        ksm[kb + 80]  = (unsigned short)k23;
        ksm[kb + 120] = (unsigned short)(k23 >> 16);
        const unsigned int p0 = cvt2(acc[2][rt][ct][0], acc[2][rt][ct][1]);
        const unsigned int p1 = cvt2(acc[2][rt][ct][2], acc[2][rt][ct][3]);
        unsigned int* vd = (unsigned int*)&vT[(ct * 16 + c0) * 136 + R + rt * 16 + 4 * g];
        vd[0] = p0; vd[1] = p1;
      }
  }

  __syncthreads();

  // ---------------- Phase 2: scores + softmax (no max-subtraction; scores are O(+-2)) ----------------
  f32x4 s[2][8];
  {
    const f32x4 zero = { 0.f, 0.f, 0.f, 0.f };
    bf16x8 aq[2];
    aq[0] = *(const bf16x8*)&pst[(c0) * 40 + 8 * g];
    aq[1] = *(const bf16x8*)&pst[(16 + c0) * 40 + 8 * g];
#pragma unroll
    for (int ct = 0; ct < 8; ++ct) {
      bf16x8 bkf = *(const bf16x8*)&ksm[(ct * 16 + c0) * 40 + 8 * g];
      s[0][ct] = __builtin_amdgcn_mfma_f32_16x16x32_bf16(aq[0], bkf, zero, 0, 0, 0);
      s[1][ct] = __builtin_amdgcn_mfma_f32_16x16x32_bf16(aq[1], bkf, zero, 0, 0, 0);
    }
  }

  float rl[2][4];
#pragma unroll
  for (int rt = 0; rt < 2; ++rt) {
#pragma unroll
    for (int r = 0; r < 4; ++r) {
      const int row = R + rt * 16 + 4 * g + r;
      float sum = 0.f;
#pragma unroll
      for (int ct = 0; ct < 8; ++ct) {
        const int col = ct * 16 + c0;
        const int d = row - col;
        const int ad = d < 0 ? -d : d;
        const float e = exp2f(s[rt][ct][r] * (0.17677669529663687f * 1.4426950408889634f) + pb[ad]);
        s[rt][ct][r] = e;
        sum += e;
      }
      sum = redsum16(sum);
      rl[rt][r] = 1.0f / sum;
    }
  }

  // ---------------- Phase 3: out = P @ v ----------------
  f32x4 o[2][2];
  {
    const f32x4 zero = { 0.f, 0.f, 0.f, 0.f };
    o[0][0] = zero; o[0][1] = zero; o[1][0] = zero; o[1][1] = zero;
#pragma unroll
    for (int ss = 0; ss < 4; ++ss) {
#pragma unroll
      for (int rt = 0; rt < 2; ++rt)
#pragma unroll
        for (int h = 0; h < 2; ++h) {
          const int ct = ss * 2 + h;
          const unsigned int a01 = cvt2(s[rt][ct][0], s[rt][ct][1]);
          const unsigned int a23 = cvt2(s[rt][ct][2], s[rt][ct][3]);
          const int base = (rt * 16 + 4 * g) * 40 + h * 16 + c0;
          pst[base]       = (unsigned short)a01;
          pst[base + 40]  = (unsigned short)(a01 >> 16);
          pst[base + 80]  = (unsigned short)a23;
          pst[base + 120] = (unsigned short)(a23 >> 16);
        }
      bf16x8 ap0 = *(const bf16x8*)&pst[(c0) * 40 + 8 * g];
      bf16x8 ap1 = *(const bf16x8*)&pst[(16 + c0) * 40 + 8 * g];
#pragma unroll
      for (int ht = 0; ht < 2; ++ht) {
        bf16x8 bv2 = *(const bf16x8*)&vT[(ht * 16 + c0) * 136 + ss * 32 + 8 * g];
        o[0][ht] = __builtin_amdgcn_mfma_f32_16x16x32_bf16(ap0, bv2, o[0][ht], 0, 0, 0);
        o[1][ht] = __builtin_amdgcn_mfma_f32_16x16x32_bf16(ap1, bv2, o[1][ht], 0, 0, 0);
      }
    }
#pragma unroll
    for (int rt = 0; rt < 2; ++rt)
#pragma unroll
      for (int ht = 0; ht < 2; ++ht)
#pragma unroll
        for (int r = 0; r < 4; ++r)
          o[rt][ht][r] *= rl[rt][r];
  }

  // ---------------- Phase 4: temporal gate ----------------
  {
#pragma unroll
    for (int rt = 0; rt < 2; ++rt)
#pragma unroll
      for (int ht = 0; ht < 2; ++ht) {
        const unsigned int a01 = cvt2(o[rt][ht][0], o[rt][ht][1]);
        const unsigned int a23 = cvt2(o[rt][ht][2], o[rt][ht][3]);
        const int base = (rt * 16 + 4 * g) * 40 + ht * 16 + c0;
        pst[base]       = (unsigned short)a01;
        pst[base + 40]  = (unsigned short)(a01 >> 16);
        pst[base + 80]  = (unsigned short)a23;
        pst[base + 120] = (unsigned short)(a23 >> 16);
      }

    bf16x8 ao0 = *(const bf16x8*)&pst[(c0) * 40 + 8 * g];
    bf16x8 ao1 = *(const bf16x8*)&pst[(16 + c0) * 40 + 8 * g];

    f32x4 gt[2][2];
#pragma unroll
    for (int ct = 0; ct < 2; ++ct) {
      const float bgv = bg[ct * 16 + c0];
      f32x4 a; a[0] = bgv; a[1] = bgv; a[2] = bgv; a[3] = bgv;
      bf16x8 f;
#pragma unroll
      for (int j = 0; j < 8; ++j) f[j] = (short)f2bf(wg[(8 * g + j) * Hh + ct * 16 + c0]);
      gt[0][ct] = __builtin_amdgcn_mfma_f32_16x16x32_bf16(ao0, f, a, 0, 0, 0);
      gt[1][ct] = __builtin_amdgcn_mfma_f32_16x16x32_bf16(ao1, f, a, 0, 0, 0);
    }
#pragma unroll
    for (int rt = 0; rt < 2; ++rt)
#pragma unroll
      for (int ct = 0; ct < 2; ++ct)
#pragma unroll
        for (int r = 0; r < 4; ++r) {
          const float sg = 1.0f / (1.0f + exp2f(gt[rt][ct][r] * -1.4426950408889634f));
          o[rt][ct][r] *= sg;
        }
  }

  // ---------------- Phase 5: y = gated @ wo + bo + residual ----------------
  f32x4 y[2][4];
  {
#pragma unroll
    for (int rt = 0; rt < 2; ++rt)
#pragma unroll
      for (int ht = 0; ht < 2; ++ht) {
        const unsigned int a01 = cvt2(o[rt][ht][0], o[rt][ht][1]);
        const unsigned int a23 = cvt2(o[rt][ht][2], o[rt][ht][3]);
        const int base = (rt * 16 + 4 * g) * 40 + ht * 16 + c0;
        pst[base]       = (unsigned short)a01;
        pst[base + 40]  = (unsigned short)(a01 >> 16);
        pst[base + 80]  = (unsigned short)a23;
        pst[base + 120] = (unsigned short)(a23 >> 16);
      }

    bf16x8 ag0 = *(const bf16x8*)&pst[(c0) * 40 + 8 * g];
    bf16x8 ag1 = *(const bf16x8*)&pst[(16 + c0) * 40 + 8 * g];

#pragma unroll
    for (int ct = 0; ct < 4; ++ct) {
      const float bov = bo[ct * 16 + c0];
      f32x4 a; a[0] = bov; a[1] = bov; a[2] = bov; a[3] = bov;
      bf16x8 f;
#pragma unroll
      for (int j = 0; j < 8; ++j) f[j] = (short)f2bf(wo[(8 * g + j) * Cc + ct * 16 + c0]);
      y[0][ct] = __builtin_amdgcn_mfma_f32_16x16x32_bf16(ag0, f, a, 0, 0, 0);
      y[1][ct] = __builtin_amdgcn_mfma_f32_16x16x32_bf16(ag1, f, a, 0, 0, 0);
    }
    // residual
#pragma unroll
    for (int rt = 0; rt < 2; ++rt)
#pragma unroll
      for (int ct = 0; ct < 4; ++ct)
#pragma unroll
        for (int r = 0; r < 4; ++r)
          y[rt][ct][r] += bf2f(xp[(R + rt * 16 + 4 * g + r) * 72 + ct * 16 + c0]);
  }

  // ---------------- Phase 6: LayerNorm over C, stage in LDS, contiguous bf16 store ----------------
  {
    float gam[4], bet[4];
#pragma unroll
    for (int ct = 0; ct < 4; ++ct) { gam[ct] = gamma[ct * 16 + c0]; bet[ct] = beta[ct * 16 + c0]; }

#pragma unroll
    for (int rt = 0; rt < 2; ++rt) {
#pragma unroll
      for (int r = 0; r < 4; ++r) {
        float sum = 0.f;
#pragma unroll
        for (int ct = 0; ct < 4; ++ct) sum += y[rt][ct][r];
        sum = redsum16(sum);
        const float mu = sum * (1.0f / 64.0f);
        float vs = 0.f;
#pragma unroll
        for (int ct = 0; ct < 4; ++ct) { const float d = y[rt][ct][r] - mu; vs += d * d; }
        vs = redsum16(vs);
        const float rs = rsqrtf(vs * (1.0f / 64.0f) + 1e-5f);
        const int row = R + rt * 16 + 4 * g + r;
#pragma unroll
        for (int ct = 0; ct < 2; ++ct) {
          const unsigned int p = cvt2((y[rt][2 * ct][r] - mu) * rs * gam[2 * ct] + bet[2 * ct],
                                      (y[rt][2 * ct + 1][r] - mu) * rs * gam[2 * ct + 1] + bet[2 * ct + 1]);
          // pair elements are 16 apart in c -> two b16 stores
          xp[row * 72 + (2 * ct) * 16 + c0]     = (unsigned short)p;
          xp[row * 72 + (2 * ct + 1) * 16 + c0] = (unsigned short)(p >> 16);
        }
      }
    }
  }

  __syncthreads();

  // contiguous bf16 tile store (in-place over this block's xt region)
  {
    const int r = tid >> 1;
    const int half = (tid & 1) * 32;
    bf16x8 v[4];
#pragma unroll
    for (int j = 0; j < 4; ++j) v[j] = *(const bf16x8*)&xp[r * 72 + half + 8 * j];
    unsigned short* dst = xtile + (size_t)r * Cc + half;
#pragma unroll
    for (int j = 0; j < 4; ++j) *(bf16x8*)(dst + 8 * j) = v[j];
  }
}

extern "C" void kernel_launch(void* const* d_in, const int* in_sizes, int n_in,
                              void* d_out, int out_size, void* d_ws, size_t ws_size,
                              hipStream_t stream) {
  const float* x = (const float*)d_in[0];
  float* out = (float*)d_out;
  unsigned short* xt = (unsigned short*)d_ws;   // 8*512*128*64 bf16 = 64 MB (R3-proven footprint)

  sta_tin<<<dim3(Nn / 64, Tt, Bq), dim3(256), 0, stream>>>(x, xt);

  sta_core<<<dim3(Bq * Nn), dim3(256), 0, stream>>>(
      xt,
      (const float*)d_in[1], (const float*)d_in[2],
      (const float*)d_in[3], (const float*)d_in[4],
      (const float*)d_in[5], (const float*)d_in[6],
      (const float*)d_in[7], (const float*)d_in[8],
      (const float*)d_in[9], (const float*)d_in[10],
      (const float*)d_in[11], (const float*)d_in[12]);

  sta_tout<<<dim3(Nn / 64, Tt, Bq), dim3(256), 0, stream>>>(xt, out);
}

// Round 12
// 176.032 us; speedup vs baseline: 1.0158x; 1.0158x over previous
//
#include <hip/hip_runtime.h>

#define Bq 8
#define Cc 64
#define Tt 128
#define Nn 512
#define Hh 32

typedef __attribute__((ext_vector_type(8))) short bf16x8;
typedef __attribute__((ext_vector_type(4))) float f32x4;
typedef __attribute__((ext_vector_type(4))) unsigned int u32x4;

typedef union { unsigned int u[4]; bf16x8 v; } frag_u;

__device__ __forceinline__ unsigned short f2bf(float f) {
  union { float f; unsigned int i; } u; u.f = f;
  unsigned int r = (u.i + 0x7FFFu + ((u.i >> 16) & 1u)) >> 16;
  return (unsigned short)r;
}
__device__ __forceinline__ float bf2f(unsigned short h) {
  union { float f; unsigned int i; } u; u.i = ((unsigned int)h) << 16; return u.f;
}
// HW packed f32->bf16 (RNE): low16 = bf16(lo), high16 = bf16(hi)
__device__ __forceinline__ unsigned int cvt2(float lo, float hi) {
  unsigned int r;
  asm("v_cvt_pk_bf16_f32 %0, %1, %2" : "=v"(r) : "v"(lo), "v"(hi));
  return r;
}
__device__ __forceinline__ float redsum16(float v) {
#pragma unroll
  for (int m = 1; m < 16; m <<= 1) v += __shfl_xor(v, m, 64);
  return v;
}

// ---------------- Pass 1: x[B,C,T,N] f32 -> xt[B,N,T,C] bf16 (tiled transpose) ----------------
__global__ __launch_bounds__(256) void sta_tin(const float* __restrict__ x,
                                               unsigned short* __restrict__ xt) {
  __shared__ float tile[64][65];
  const int tid = threadIdx.x;
  const int nb = blockIdx.x, t = blockIdx.y, b = blockIdx.z;
  const int n0 = nb * 64;

#pragma unroll
  for (int i = 0; i < 4; ++i) {
    const int c = i * 16 + (tid >> 4);
    const int nf = (tid & 15) * 4;
    const float4 v = *(const float4*)(x + (((size_t)(b * Cc + c) * Tt + t) * Nn + n0 + nf));
    tile[c][nf + 0] = v.x; tile[c][nf + 1] = v.y; tile[c][nf + 2] = v.z; tile[c][nf + 3] = v.w;
  }
  __syncthreads();

  const int np = tid >> 2;
  const int cq = (tid & 3) * 16;
  unsigned int u[8];
#pragma unroll
  for (int k = 0; k < 8; ++k)
    u[k] = cvt2(tile[cq + 2 * k][np], tile[cq + 2 * k + 1][np]);
  unsigned short* dst = xt + (((size_t)(b * Nn + n0 + np) * Tt + t) * Cc + cq);
  u32x4 s0 = { u[0], u[1], u[2], u[3] };
  u32x4 s1 = { u[4], u[5], u[6], u[7] };
  *(u32x4*)(dst) = s0;
  *(u32x4*)(dst + 8) = s1;
}

// ---------------- Pass 3: yt[B,N,T,C] bf16 -> out[B,C,T,N] f32 (tiled transpose) ----------------
__global__ __launch_bounds__(256) void sta_tout(const unsigned short* __restrict__ yt,
                                                float* __restrict__ out) {
  __shared__ float tile[64][65];
  const int tid = threadIdx.x;
  const int nb = blockIdx.x, t = blockIdx.y, b = blockIdx.z;
  const int n0 = nb * 64;

  {
    const int np = tid >> 2;
    const int cq = (tid & 3) * 16;
    const unsigned short* src = yt + (((size_t)(b * Nn + n0 + np) * Tt + t) * Cc + cq);
    const bf16x8 v0 = *(const bf16x8*)(src);
    const bf16x8 v1 = *(const bf16x8*)(src + 8);
#pragma unroll
    for (int j = 0; j < 8; ++j) {
      tile[np][cq + j]     = bf2f((unsigned short)v0[j]);
      tile[np][cq + 8 + j] = bf2f((unsigned short)v1[j]);
    }
  }
  __syncthreads();

  const int c = tid >> 2;
  const int nq = (tid & 3) * 16;
#pragma unroll
  for (int k = 0; k < 4; ++k) {
    float4 w;
    w.x = tile[nq + 4 * k + 0][c];
    w.y = tile[nq + 4 * k + 1][c];
    w.z = tile[nq + 4 * k + 2][c];
    w.w = tile[nq + 4 * k + 3][c];
    *(float4*)(out + (((size_t)(b * Cc + c) * Tt + t) * Nn + n0 + nq + 4 * k)) = w;
  }
}

// ---------------- Pass 2: fused attention on contiguous bf16 tiles (in-place xt -> yt) ----------------
__global__ __launch_bounds__(256, 3) void sta_core(
    unsigned short* __restrict__ xt,
    const float* __restrict__ wq, const float* __restrict__ bq,
    const float* __restrict__ wk, const float* __restrict__ bk,
    const float* __restrict__ wv, const float* __restrict__ bv,
    const float* __restrict__ wg, const float* __restrict__ bg,
    const float* __restrict__ wo, const float* __restrict__ bo,
    const float* __restrict__ gamma, const float* __restrict__ beta)
{
  __shared__ __align__(16) unsigned short xp[Tt * 72];     // xp[t][c]   18,432 B
  __shared__ __align__(16) unsigned short ksm[Tt * 40];    // k[t][h]    10,240 B
  __shared__ __align__(16) unsigned short vT[Hh * 136];    // vT[h][s]    8,704 B
  __shared__ __align__(16) unsigned short stg[4 * 32 * 40];// per-wave   10,240 B
  __shared__ float pb[128];                                // posbias*log2e  512 B

  const int tid  = threadIdx.x;
  const int lane = tid & 63;
  const int w    = tid >> 6;
  const int g    = lane >> 4;
  const int c0   = lane & 15;
  const int R    = w * 32;

  unsigned short* xtile = xt + (size_t)blockIdx.x * (Tt * Cc);

  // ---------------- Phase 0: contiguous 16KB tile -> LDS ----------------
  {
    const int r = tid >> 1;
    const int half = (tid & 1) * 32;
    const unsigned short* src = xtile + (size_t)r * Cc + half;
    bf16x8 v[4];
#pragma unroll
    for (int j = 0; j < 4; ++j) v[j] = *(const bf16x8*)(src + 8 * j);
#pragma unroll
    for (int j = 0; j < 4; ++j) *(bf16x8*)&xp[r * 72 + half + 8 * j] = v[j];
  }

  // position-bias table: pb[d] = exp(-d/128) * log2(e)  (additive exponent, exp2 domain)
  if (tid < 128) pb[tid] = exp2f((float)tid * -0.0112710550069f) * 1.4426950408889634f;

  // QKV weight B-fragments, built in-kernel exactly where R6 builds them.
  // Only the conversion is changed: HW v_cvt_pk_bf16_f32 pairs instead of manual f2bf.
  bf16x8 bwf[3][2][2];      // [q/k/v][ct][kstep]
  float  bias0[3][2];
  {
    const float* ws3[3] = { wq, wk, wv };
    const float* bs3[3] = { bq, bk, bv };
#pragma unroll
    for (int o = 0; o < 3; ++o) {
#pragma unroll
      for (int ct = 0; ct < 2; ++ct) {
        bias0[o][ct] = bs3[o][ct * 16 + c0];
#pragma unroll
        for (int ks2 = 0; ks2 < 2; ++ks2) {
          const float* m = ws3[o] + (ks2 * 32 + 8 * g) * Hh + ct * 16 + c0;
          frag_u cv;
#pragma unroll
          for (int p = 0; p < 4; ++p)
            cv.u[p] = cvt2(m[(2 * p) * Hh], m[(2 * p + 1) * Hh]);
          bwf[o][ct][ks2] = cv.v;
        }
      }
    }
  }

  __syncthreads();

  // ---------------- Phase 1: QKV = xp @ {wq,wk,wv} + bias ----------------
  unsigned short* pst = &stg[w * 1280];
  {
    f32x4 acc[3][2][2];
#pragma unroll
    for (int o = 0; o < 3; ++o)
#pragma unroll
      for (int rt = 0; rt < 2; ++rt)
#pragma unroll
        for (int ct = 0; ct < 2; ++ct) {
          f32x4 a; a[0] = bias0[o][ct]; a[1] = bias0[o][ct]; a[2] = bias0[o][ct]; a[3] = bias0[o][ct];
          acc[o][rt][ct] = a;
        }
    bf16x8 af[2][2];
#pragma unroll
    for (int rt = 0; rt < 2; ++rt)
#pragma unroll
      for (int ks2 = 0; ks2 < 2; ++ks2)
        af[rt][ks2] = *(const bf16x8*)&xp[(R + rt * 16 + c0) * 72 + ks2 * 32 + 8 * g];
#pragma unroll
    for (int o = 0; o < 3; ++o)
#pragma unroll
      for (int rt = 0; rt < 2; ++rt)
#pragma unroll
        for (int ct = 0; ct < 2; ++ct)
#pragma unroll
          for (int ks2 = 0; ks2 < 2; ++ks2)
            acc[o][rt][ct] = __builtin_amdgcn_mfma_f32_16x16x32_bf16(af[rt][ks2], bwf[o][ct][ks2], acc[o][rt][ct], 0, 0, 0);

    // scatter D-frags via packed cvt: q -> pst, k -> ksm, v -> vT (transposed)
#pragma unroll
    for (int rt = 0; rt < 2; ++rt)
#pragma unroll
      for (int ct = 0; ct < 2; ++ct) {
        const unsigned int q01 = cvt2(acc[0][rt][ct][0], acc[0][rt][ct][1]);
        const unsigned int q23 = cvt2(acc[0][rt][ct][2], acc[0][rt][ct][3]);
        const unsigned int k01 = cvt2(acc[1][rt][ct][0], acc[1][rt][ct][1]);
        const unsigned int k23 = cvt2(acc[1][rt][ct][2], acc[1][rt][ct][3]);
        const int qb = (rt * 16 + 4 * g) * 40 + ct * 16 + c0;
        pst[qb]       = (unsigned short)q01;
        pst[qb + 40]  = (unsigned short)(q01 >> 16);
        pst[qb + 80]  = (unsigned short)q23;
        pst[qb + 120] = (unsigned short)(q23 >> 16);
        const int kb = (R + rt * 16 + 4 * g) * 40 + ct * 16 + c0;
        ksm[kb]       = (unsigned short)k01;
        ksm[kb + 40]  = (unsigned short)(k01 >> 16);
        ksm[kb + 80]  = (unsigned short)k23;
        ksm[kb + 120] = (unsigned short)(k23 >> 16);
        const unsigned int p0 = cvt2(acc[2][rt][ct][0], acc[2][rt][ct][1]);
        const unsigned int p1 = cvt2(acc[2][rt][ct][2], acc[2][rt][ct][3]);
        unsigned int* vd = (unsigned int*)&vT[(ct * 16 + c0) * 136 + R + rt * 16 + 4 * g];
        vd[0] = p0; vd[1] = p1;
      }
  }

  __syncthreads();

  // ---------------- Phase 2: scores + softmax (no max-subtraction; scores are O(+-2)) ----------------
  f32x4 s[2][8];
  {
    const f32x4 zero = { 0.f, 0.f, 0.f, 0.f };
    bf16x8 aq[2];
    aq[0] = *(const bf16x8*)&pst[(c0) * 40 + 8 * g];
    aq[1] = *(const bf16x8*)&pst[(16 + c0) * 40 + 8 * g];
#pragma unroll
    for (int ct = 0; ct < 8; ++ct) {
      bf16x8 bkf = *(const bf16x8*)&ksm[(ct * 16 + c0) * 40 + 8 * g];
      s[0][ct] = __builtin_amdgcn_mfma_f32_16x16x32_bf16(aq[0], bkf, zero, 0, 0, 0);
      s[1][ct] = __builtin_amdgcn_mfma_f32_16x16x32_bf16(aq[1], bkf, zero, 0, 0, 0);
    }
  }

  float rl[2][4];
#pragma unroll
  for (int rt = 0; rt < 2; ++rt) {
#pragma unroll
    for (int r = 0; r < 4; ++r) {
      const int row = R + rt * 16 + 4 * g + r;
      float sum = 0.f;
#pragma unroll
      for (int ct = 0; ct < 8; ++ct) {
        const int col = ct * 16 + c0;
        const int d = row - col;
        const int ad = d < 0 ? -d : d;
        const float e = exp2f(s[rt][ct][r] * (0.17677669529663687f * 1.4426950408889634f) + pb[ad]);
        s[rt][ct][r] = e;
        sum += e;
      }
      sum = redsum16(sum);
      rl[rt][r] = 1.0f / sum;
    }
  }

  // ---------------- Phase 3: out = P @ v ----------------
  f32x4 o[2][2];
  {
    const f32x4 zero = { 0.f, 0.f, 0.f, 0.f };
    o[0][0] = zero; o[0][1] = zero; o[1][0] = zero; o[1][1] = zero;
#pragma unroll
    for (int ss = 0; ss < 4; ++ss) {
#pragma unroll
      for (int rt = 0; rt < 2; ++rt)
#pragma unroll
        for (int h = 0; h < 2; ++h) {
          const int ct = ss * 2 + h;
          const unsigned int a01 = cvt2(s[rt][ct][0], s[rt][ct][1]);
          const unsigned int a23 = cvt2(s[rt][ct][2], s[rt][ct][3]);
          const int base = (rt * 16 + 4 * g) * 40 + h * 16 + c0;
          pst[base]       = (unsigned short)a01;
          pst[base + 40]  = (unsigned short)(a01 >> 16);
          pst[base + 80]  = (unsigned short)a23;
          pst[base + 120] = (unsigned short)(a23 >> 16);
        }
      bf16x8 ap0 = *(const bf16x8*)&pst[(c0) * 40 + 8 * g];
      bf16x8 ap1 = *(const bf16x8*)&pst[(16 + c0) * 40 + 8 * g];
#pragma unroll
      for (int ht = 0; ht < 2; ++ht) {
        bf16x8 bv2 = *(const bf16x8*)&vT[(ht * 16 + c0) * 136 + ss * 32 + 8 * g];
        o[0][ht] = __builtin_amdgcn_mfma_f32_16x16x32_bf16(ap0, bv2, o[0][ht], 0, 0, 0);
        o[1][ht] = __builtin_amdgcn_mfma_f32_16x16x32_bf16(ap1, bv2, o[1][ht], 0, 0, 0);
      }
    }
#pragma unroll
    for (int rt = 0; rt < 2; ++rt)
#pragma unroll
      for (int ht = 0; ht < 2; ++ht)
#pragma unroll
        for (int r = 0; r < 4; ++r)
          o[rt][ht][r] *= rl[rt][r];
  }

  // ---------------- Phase 4: temporal gate ----------------
  {
#pragma unroll
    for (int rt = 0; rt < 2; ++rt)
#pragma unroll
      for (int ht = 0; ht < 2; ++ht) {
        const unsigned int a01 = cvt2(o[rt][ht][0], o[rt][ht][1]);
        const unsigned int a23 = cvt2(o[rt][ht][2], o[rt][ht][3]);
        const int base = (rt * 16 + 4 * g) * 40 + ht * 16 + c0;
        pst[base]       = (unsigned short)a01;
        pst[base + 40]  = (unsigned short)(a01 >> 16);
        pst[base + 80]  = (unsigned short)a23;
        pst[base + 120] = (unsigned short)(a23 >> 16);
      }

    bf16x8 ao0 = *(const bf16x8*)&pst[(c0) * 40 + 8 * g];
    bf16x8 ao1 = *(const bf16x8*)&pst[(16 + c0) * 40 + 8 * g];

    f32x4 gt[2][2];
#pragma unroll
    for (int ct = 0; ct < 2; ++ct) {
      const float bgv = bg[ct * 16 + c0];
      f32x4 a; a[0] = bgv; a[1] = bgv; a[2] = bgv; a[3] = bgv;
      const float* m = wg + (8 * g) * Hh + ct * 16 + c0;
      frag_u cv;
#pragma unroll
      for (int p = 0; p < 4; ++p)
        cv.u[p] = cvt2(m[(2 * p) * Hh], m[(2 * p + 1) * Hh]);
      gt[0][ct] = __builtin_amdgcn_mfma_f32_16x16x32_bf16(ao0, cv.v, a, 0, 0, 0);
      gt[1][ct] = __builtin_amdgcn_mfma_f32_16x16x32_bf16(ao1, cv.v, a, 0, 0, 0);
    }
#pragma unroll
    for (int rt = 0; rt < 2; ++rt)
#pragma unroll
      for (int ct = 0; ct < 2; ++ct)
#pragma unroll
        for (int r = 0; r < 4; ++r) {
          const float sg = 1.0f / (1.0f + exp2f(gt[rt][ct][r] * -1.4426950408889634f));
          o[rt][ct][r] *= sg;
        }
  }

  // ---------------- Phase 5: y = gated @ wo + bo + residual ----------------
  f32x4 y[2][4];
  {
#pragma unroll
    for (int rt = 0; rt < 2; ++rt)
#pragma unroll
      for (int ht = 0; ht < 2; ++ht) {
        const unsigned int a01 = cvt2(o[rt][ht][0], o[rt][ht][1]);
        const unsigned int a23 = cvt2(o[rt][ht][2], o[rt][ht][3]);
        const int base = (rt * 16 + 4 * g) * 40 + ht * 16 + c0;
        pst[base]       = (unsigned short)a01;
        pst[base + 40]  = (unsigned short)(a01 >> 16);
        pst[base + 80]  = (unsigned short)a23;
        pst[base + 120] = (unsigned short)(a23 >> 16);
      }

    bf16x8 ag0 = *(const bf16x8*)&pst[(c0) * 40 + 8 * g];
    bf16x8 ag1 = *(const bf16x8*)&pst[(16 + c0) * 40 + 8 * g];

#pragma unroll
    for (int ct = 0; ct < 4; ++ct) {
      const float bov = bo[ct * 16 + c0];
      f32x4 a; a[0] = bov; a[1] = bov; a[2] = bov; a[3] = bov;
      const float* m = wo + (8 * g) * Cc + ct * 16 + c0;
      frag_u cv;
#pragma unroll
      for (int p = 0; p < 4; ++p)
        cv.u[p] = cvt2(m[(2 * p) * Cc], m[(2 * p + 1) * Cc]);
      y[0][ct] = __builtin_amdgcn_mfma_f32_16x16x32_bf16(ag0, cv.v, a, 0, 0, 0);
      y[1][ct] = __builtin_amdgcn_mfma_f32_16x16x32_bf16(ag1, cv.v, a, 0, 0, 0);
    }
    // residual
#pragma unroll
    for (int rt = 0; rt < 2; ++rt)
#pragma unroll
      for (int ct = 0; ct < 4; ++ct)
#pragma unroll
        for (int r = 0; r < 4; ++r)
          y[rt][ct][r] += bf2f(xp[(R + rt * 16 + 4 * g + r) * 72 + ct * 16 + c0]);
  }

  // ---------------- Phase 6: LayerNorm over C, stage in LDS, contiguous bf16 store ----------------
  {
    float gam[4], bet[4];
#pragma unroll
    for (int ct = 0; ct < 4; ++ct) { gam[ct] = gamma[ct * 16 + c0]; bet[ct] = beta[ct * 16 + c0]; }

#pragma unroll
    for (int rt = 0; rt < 2; ++rt) {
#pragma unroll
      for (int r = 0; r < 4; ++r) {
        float sum = 0.f;
#pragma unroll
        for (int ct = 0; ct < 4; ++ct) sum += y[rt][ct][r];
        sum = redsum16(sum);
        const float mu = sum * (1.0f / 64.0f);
        float vs = 0.f;
#pragma unroll
        for (int ct = 0; ct < 4; ++ct) { const float d = y[rt][ct][r] - mu; vs += d * d; }
        vs = redsum16(vs);
        const float rs = rsqrtf(vs * (1.0f / 64.0f) + 1e-5f);
        const int row = R + rt * 16 + 4 * g + r;
#pragma unroll
        for (int ct = 0; ct < 2; ++ct) {
          const unsigned int p = cvt2((y[rt][2 * ct][r] - mu) * rs * gam[2 * ct] + bet[2 * ct],
                                      (y[rt][2 * ct + 1][r] - mu) * rs * gam[2 * ct + 1] + bet[2 * ct + 1]);
          // pair elements are 16 apart in c -> two b16 stores
          xp[row * 72 + (2 * ct) * 16 + c0]     = (unsigned short)p;
          xp[row * 72 + (2 * ct + 1) * 16 + c0] = (unsigned short)(p >> 16);
        }
      }
    }
  }

  __syncthreads();

  // contiguous bf16 tile store (in-place over this block's xt region)
  {
    const int r = tid >> 1;
    const int half = (tid & 1) * 32;
    bf16x8 v[4];
#pragma unroll
    for (int j = 0; j < 4; ++j) v[j] = *(const bf16x8*)&xp[r * 72 + half + 8 * j];
    unsigned short* dst = xtile + (size_t)r * Cc + half;
#pragma unroll
    for (int j = 0; j < 4; ++j) *(bf16x8*)(dst + 8 * j) = v[j];
  }
}

extern "C" void kernel_launch(void* const* d_in, const int* in_sizes, int n_in,
                              void* d_out, int out_size, void* d_ws, size_t ws_size,
                              hipStream_t stream) {
  const float* x = (const float*)d_in[0];
  float* out = (float*)d_out;
  unsigned short* xt = (unsigned short*)d_ws;   // 8*512*128*64 bf16 = 64 MB (proven footprint)

  sta_tin<<<dim3(Nn / 64, Tt, Bq), dim3(256), 0, stream>>>(x, xt);

  sta_core<<<dim3(Bq * Nn), dim3(256), 0, stream>>>(
      xt,
      (const float*)d_in[1], (const float*)d_in[2],
      (const float*)d_in[3], (const float*)d_in[4],
      (const float*)d_in[5], (const float*)d_in[6],
      (const float*)d_in[7], (const float*)d_in[8],
      (const float*)d_in[9], (const float*)d_in[10],
      (const float*)d_in[11], (const float*)d_in[12]);

  sta_tout<<<dim3(Nn / 64, Tt, Bq), dim3(256), 0, stream>>>(xt, out);
}

// Round 13
// 172.262 us; speedup vs baseline: 1.0381x; 1.0219x over previous
//
#include <hip/hip_runtime.h>

#define Bq 8
#define Cc 64
#define Tt 128
#define Nn 512
#define Hh 32

typedef __attribute__((ext_vector_type(8))) short bf16x8;
typedef __attribute__((ext_vector_type(4))) float f32x4;
typedef __attribute__((ext_vector_type(4))) unsigned int u32x4;

typedef union { unsigned int u[4]; bf16x8 v; } frag_u;

__device__ __forceinline__ unsigned short f2bf(float f) {
  union { float f; unsigned int i; } u; u.f = f;
  unsigned int r = (u.i + 0x7FFFu + ((u.i >> 16) & 1u)) >> 16;
  return (unsigned short)r;
}
__device__ __forceinline__ float bf2f(unsigned short h) {
  union { float f; unsigned int i; } u; u.i = ((unsigned int)h) << 16; return u.f;
}
// HW packed f32->bf16 (RNE): low16 = bf16(lo), high16 = bf16(hi)
__device__ __forceinline__ unsigned int cvt2(float lo, float hi) {
  unsigned int r;
  asm("v_cvt_pk_bf16_f32 %0, %1, %2" : "=v"(r) : "v"(lo), "v"(hi));
  return r;
}
__device__ __forceinline__ float redsum16(float v) {
#pragma unroll
  for (int m = 1; m < 16; m <<= 1) v += __shfl_xor(v, m, 64);
  return v;
}

// ---------------- Pass 1: x[B,C,T,N] f32 -> xt[B,N,T,C] bf16 (tiled transpose) ----------------
__global__ __launch_bounds__(256) void sta_tin(const float* __restrict__ x,
                                               unsigned short* __restrict__ xt) {
  __shared__ float tile[64][65];
  const int tid = threadIdx.x;
  const int nb = blockIdx.x, t = blockIdx.y, b = blockIdx.z;
  const int n0 = nb * 64;

#pragma unroll
  for (int i = 0; i < 4; ++i) {
    const int c = i * 16 + (tid >> 4);
    const int nf = (tid & 15) * 4;
    const float4 v = *(const float4*)(x + (((size_t)(b * Cc + c) * Tt + t) * Nn + n0 + nf));
    tile[c][nf + 0] = v.x; tile[c][nf + 1] = v.y; tile[c][nf + 2] = v.z; tile[c][nf + 3] = v.w;
  }
  __syncthreads();

  const int np = tid >> 2;
  const int cq = (tid & 3) * 16;
  unsigned int u[8];
#pragma unroll
  for (int k = 0; k < 8; ++k)
    u[k] = cvt2(tile[cq + 2 * k][np], tile[cq + 2 * k + 1][np]);
  unsigned short* dst = xt + (((size_t)(b * Nn + n0 + np) * Tt + t) * Cc + cq);
  u32x4 s0 = { u[0], u[1], u[2], u[3] };
  u32x4 s1 = { u[4], u[5], u[6], u[7] };
  *(u32x4*)(dst) = s0;
  *(u32x4*)(dst + 8) = s1;
}

// ---------------- Pass 3: yt[B,N,T,C] bf16 -> out[B,C,T,N] f32 (tiled transpose) ----------------
__global__ __launch_bounds__(256) void sta_tout(const unsigned short* __restrict__ yt,
                                                float* __restrict__ out) {
  __shared__ float tile[64][65];
  const int tid = threadIdx.x;
  const int nb = blockIdx.x, t = blockIdx.y, b = blockIdx.z;
  const int n0 = nb * 64;

  {
    const int np = tid >> 2;
    const int cq = (tid & 3) * 16;
    const unsigned short* src = yt + (((size_t)(b * Nn + n0 + np) * Tt + t) * Cc + cq);
    const bf16x8 v0 = *(const bf16x8*)(src);
    const bf16x8 v1 = *(const bf16x8*)(src + 8);
#pragma unroll
    for (int j = 0; j < 8; ++j) {
      tile[np][cq + j]     = bf2f((unsigned short)v0[j]);
      tile[np][cq + 8 + j] = bf2f((unsigned short)v1[j]);
    }
  }
  __syncthreads();

  const int c = tid >> 2;
  const int nq = (tid & 3) * 16;
#pragma unroll
  for (int k = 0; k < 4; ++k) {
    float4 w;
    w.x = tile[nq + 4 * k + 0][c];
    w.y = tile[nq + 4 * k + 1][c];
    w.z = tile[nq + 4 * k + 2][c];
    w.w = tile[nq + 4 * k + 3][c];
    *(float4*)(out + (((size_t)(b * Cc + c) * Tt + t) * Nn + n0 + nq + 4 * k)) = w;
  }
}

// ---------------- Pass 2: fused attention on contiguous bf16 tiles (in-place xt -> yt) ----------------
__global__ __launch_bounds__(256, 3) void sta_core(
    unsigned short* __restrict__ xt,
    const float* __restrict__ wq, const float* __restrict__ bq,
    const float* __restrict__ wk, const float* __restrict__ bk,
    const float* __restrict__ wv, const float* __restrict__ bv,
    const float* __restrict__ wg, const float* __restrict__ bg,
    const float* __restrict__ wo, const float* __restrict__ bo,
    const float* __restrict__ gamma, const float* __restrict__ beta)
{
  __shared__ __align__(16) unsigned short xp[Tt * 72];     // xp[t][c]   18,432 B
  __shared__ __align__(16) unsigned short ksm[Tt * 40];    // k[t][h]    10,240 B
  __shared__ __align__(16) unsigned short vT[Hh * 136];    // vT[h][s]    8,704 B
  __shared__ __align__(16) unsigned short stg[4 * 32 * 40];// per-wave   10,240 B
  __shared__ float pb[128];                                // posbias*log2e  512 B

  const int tid  = threadIdx.x;
  const int lane = tid & 63;
  const int w    = tid >> 6;
  const int g    = lane >> 4;
  const int c0   = lane & 15;
  const int R    = w * 32;

  unsigned short* xtile = xt + (size_t)blockIdx.x * (Tt * Cc);

  // ---------------- Phase 0: contiguous 16KB tile -> LDS ----------------
  {
    const int r = tid >> 1;
    const int half = (tid & 1) * 32;
    const unsigned short* src = xtile + (size_t)r * Cc + half;
    bf16x8 v[4];
#pragma unroll
    for (int j = 0; j < 4; ++j) v[j] = *(const bf16x8*)(src + 8 * j);
#pragma unroll
    for (int j = 0; j < 4; ++j) *(bf16x8*)&xp[r * 72 + half + 8 * j] = v[j];
  }

  // position-bias table: pb[d] = exp(-d/128) * log2(e)  (additive exponent, exp2 domain)
  if (tid < 128) pb[tid] = exp2f((float)tid * -0.0112710550069f) * 1.4426950408889634f;

  // QKV weight B-fragments, built in-kernel exactly where R6 builds them (frozen structure).
  bf16x8 bwf[3][2][2];      // [q/k/v][ct][kstep]
  float  bias0[3][2];
  {
    const float* ws3[3] = { wq, wk, wv };
    const float* bs3[3] = { bq, bk, bv };
#pragma unroll
    for (int o = 0; o < 3; ++o) {
#pragma unroll
      for (int ct = 0; ct < 2; ++ct) {
        bias0[o][ct] = bs3[o][ct * 16 + c0];
#pragma unroll
        for (int ks2 = 0; ks2 < 2; ++ks2) {
          const float* m = ws3[o] + (ks2 * 32 + 8 * g) * Hh + ct * 16 + c0;
          frag_u cv;
#pragma unroll
          for (int p = 0; p < 4; ++p)
            cv.u[p] = cvt2(m[(2 * p) * Hh], m[(2 * p + 1) * Hh]);
          bwf[o][ct][ks2] = cv.v;
        }
      }
    }
  }

  __syncthreads();

  // ---------------- Phase 1: QKV = xp @ {wq,wk,wv} + bias ----------------
  unsigned short* pst = &stg[w * 1280];
  {
    f32x4 acc[3][2][2];
#pragma unroll
    for (int o = 0; o < 3; ++o)
#pragma unroll
      for (int rt = 0; rt < 2; ++rt)
#pragma unroll
        for (int ct = 0; ct < 2; ++ct) {
          f32x4 a; a[0] = bias0[o][ct]; a[1] = bias0[o][ct]; a[2] = bias0[o][ct]; a[3] = bias0[o][ct];
          acc[o][rt][ct] = a;
        }
    bf16x8 af[2][2];
#pragma unroll
    for (int rt = 0; rt < 2; ++rt)
#pragma unroll
      for (int ks2 = 0; ks2 < 2; ++ks2)
        af[rt][ks2] = *(const bf16x8*)&xp[(R + rt * 16 + c0) * 72 + ks2 * 32 + 8 * g];
#pragma unroll
    for (int o = 0; o < 3; ++o)
#pragma unroll
      for (int rt = 0; rt < 2; ++rt)
#pragma unroll
        for (int ct = 0; ct < 2; ++ct)
#pragma unroll
          for (int ks2 = 0; ks2 < 2; ++ks2)
            acc[o][rt][ct] = __builtin_amdgcn_mfma_f32_16x16x32_bf16(af[rt][ks2], bwf[o][ct][ks2], acc[o][rt][ct], 0, 0, 0);

    // scatter D-frags via packed cvt: q -> pst, k -> ksm, v -> vT (transposed)
#pragma unroll
    for (int rt = 0; rt < 2; ++rt)
#pragma unroll
      for (int ct = 0; ct < 2; ++ct) {
        const unsigned int q01 = cvt2(acc[0][rt][ct][0], acc[0][rt][ct][1]);
        const unsigned int q23 = cvt2(acc[0][rt][ct][2], acc[0][rt][ct][3]);
        const unsigned int k01 = cvt2(acc[1][rt][ct][0], acc[1][rt][ct][1]);
        const unsigned int k23 = cvt2(acc[1][rt][ct][2], acc[1][rt][ct][3]);
        const int qb = (rt * 16 + 4 * g) * 40 + ct * 16 + c0;
        pst[qb]       = (unsigned short)q01;
        pst[qb + 40]  = (unsigned short)(q01 >> 16);
        pst[qb + 80]  = (unsigned short)q23;
        pst[qb + 120] = (unsigned short)(q23 >> 16);
        const int kb = (R + rt * 16 + 4 * g) * 40 + ct * 16 + c0;
        ksm[kb]       = (unsigned short)k01;
        ksm[kb + 40]  = (unsigned short)(k01 >> 16);
        ksm[kb + 80]  = (unsigned short)k23;
        ksm[kb + 120] = (unsigned short)(k23 >> 16);
        const unsigned int p0 = cvt2(acc[2][rt][ct][0], acc[2][rt][ct][1]);
        const unsigned int p1 = cvt2(acc[2][rt][ct][2], acc[2][rt][ct][3]);
        unsigned int* vd = (unsigned int*)&vT[(ct * 16 + c0) * 136 + R + rt * 16 + 4 * g];
        vd[0] = p0; vd[1] = p1;
      }
  }

  __syncthreads();

  // ---------------- Phase 2: S^T = K.Q^T (swapped operands), lane-local softmax ----------------
  // D-frag of S^T: lane (g,c0) reg r holds S[q = R + rt*16 + c0][s = ct*16 + 4*g + r].
  f32x4 s[2][8];
  {
    const f32x4 zero = { 0.f, 0.f, 0.f, 0.f };
    bf16x8 aq[2];
    aq[0] = *(const bf16x8*)&pst[(c0) * 40 + 8 * g];
    aq[1] = *(const bf16x8*)&pst[(16 + c0) * 40 + 8 * g];
#pragma unroll
    for (int ct = 0; ct < 8; ++ct) {
      bf16x8 bkf = *(const bf16x8*)&ksm[(ct * 16 + c0) * 40 + 8 * g];
      s[0][ct] = __builtin_amdgcn_mfma_f32_16x16x32_bf16(bkf, aq[0], zero, 0, 0, 0);
      s[1][ct] = __builtin_amdgcn_mfma_f32_16x16x32_bf16(bkf, aq[1], zero, 0, 0, 0);
    }
  }

  float rl[2];
#pragma unroll
  for (int rt = 0; rt < 2; ++rt) {
    const int tq = R + rt * 16 + c0;      // this lane's q row (fixed)
    float sum = 0.f;
#pragma unroll
    for (int ct = 0; ct < 8; ++ct) {
      const int sb = ct * 16 + 4 * g;
#pragma unroll
      for (int r = 0; r < 4; ++r) {
        const int d = tq - (sb + r);
        const int ad = d < 0 ? -d : d;
        const float e = exp2f(s[rt][ct][r] * (0.17677669529663687f * 1.4426950408889634f) + pb[ad]);
        s[rt][ct][r] = e;
        sum += e;
      }
    }
    sum += __shfl_xor(sum, 16, 64);       // sum across the 4 g-groups (same c0)
    sum += __shfl_xor(sum, 32, 64);
    rl[rt] = 1.0f / sum;
  }

  // ---------------- Phase 3: out = P @ v; P staged [q=c0][s] via b64 (rl pre-folded) ----------------
  f32x4 o[2][2];
  {
    const f32x4 zero = { 0.f, 0.f, 0.f, 0.f };
    o[0][0] = zero; o[0][1] = zero; o[1][0] = zero; o[1][1] = zero;
#pragma unroll
    for (int ss = 0; ss < 4; ++ss) {
#pragma unroll
      for (int rt = 0; rt < 2; ++rt)
#pragma unroll
        for (int lct = 0; lct < 2; ++lct) {
          const int ct = ss * 2 + lct;
          const unsigned int a01 = cvt2(s[rt][ct][0] * rl[rt], s[rt][ct][1] * rl[rt]);
          const unsigned int a23 = cvt2(s[rt][ct][2] * rl[rt], s[rt][ct][3] * rl[rt]);
          // P[q = c0][s_local = lct*16 + 4g + r]: 4 consecutive shorts -> one b64
          unsigned int* pd = (unsigned int*)&pst[rt * 640 + c0 * 40 + lct * 16 + 4 * g];
          pd[0] = a01; pd[1] = a23;
        }
      bf16x8 ap0 = *(const bf16x8*)&pst[c0 * 40 + 8 * g];
      bf16x8 ap1 = *(const bf16x8*)&pst[640 + c0 * 40 + 8 * g];
#pragma unroll
      for (int ht = 0; ht < 2; ++ht) {
        bf16x8 bv2 = *(const bf16x8*)&vT[(ht * 16 + c0) * 136 + ss * 32 + 8 * g];
        o[0][ht] = __builtin_amdgcn_mfma_f32_16x16x32_bf16(ap0, bv2, o[0][ht], 0, 0, 0);
        o[1][ht] = __builtin_amdgcn_mfma_f32_16x16x32_bf16(ap1, bv2, o[1][ht], 0, 0, 0);
      }
    }
    // rl already folded into P; o D-frag layout identical to before (row q = R+rt*16+4g+r, col h = ht*16+c0)
  }

  // ---------------- Phase 4: temporal gate ----------------
  {
#pragma unroll
    for (int rt = 0; rt < 2; ++rt)
#pragma unroll
      for (int ht = 0; ht < 2; ++ht) {
        const unsigned int a01 = cvt2(o[rt][ht][0], o[rt][ht][1]);
        const unsigned int a23 = cvt2(o[rt][ht][2], o[rt][ht][3]);
        const int base = (rt * 16 + 4 * g) * 40 + ht * 16 + c0;
        pst[base]       = (unsigned short)a01;
        pst[base + 40]  = (unsigned short)(a01 >> 16);
        pst[base + 80]  = (unsigned short)a23;
        pst[base + 120] = (unsigned short)(a23 >> 16);
      }

    bf16x8 ao0 = *(const bf16x8*)&pst[(c0) * 40 + 8 * g];
    bf16x8 ao1 = *(const bf16x8*)&pst[(16 + c0) * 40 + 8 * g];

    f32x4 gt[2][2];
#pragma unroll
    for (int ct = 0; ct < 2; ++ct) {
      const float bgv = bg[ct * 16 + c0];
      f32x4 a; a[0] = bgv; a[1] = bgv; a[2] = bgv; a[3] = bgv;
      const float* m = wg + (8 * g) * Hh + ct * 16 + c0;
      frag_u cv;
#pragma unroll
      for (int p = 0; p < 4; ++p)
        cv.u[p] = cvt2(m[(2 * p) * Hh], m[(2 * p + 1) * Hh]);
      gt[0][ct] = __builtin_amdgcn_mfma_f32_16x16x32_bf16(ao0, cv.v, a, 0, 0, 0);
      gt[1][ct] = __builtin_amdgcn_mfma_f32_16x16x32_bf16(ao1, cv.v, a, 0, 0, 0);
    }
#pragma unroll
    for (int rt = 0; rt < 2; ++rt)
#pragma unroll
      for (int ct = 0; ct < 2; ++ct)
#pragma unroll
        for (int r = 0; r < 4; ++r) {
          const float sg = 1.0f / (1.0f + exp2f(gt[rt][ct][r] * -1.4426950408889634f));
          o[rt][ct][r] *= sg;
        }
  }

  // ---------------- Phase 5: y = gated @ wo + bo + residual ----------------
  f32x4 y[2][4];
  {
#pragma unroll
    for (int rt = 0; rt < 2; ++rt)
#pragma unroll
      for (int ht = 0; ht < 2; ++ht) {
        const unsigned int a01 = cvt2(o[rt][ht][0], o[rt][ht][1]);
        const unsigned int a23 = cvt2(o[rt][ht][2], o[rt][ht][3]);
        const int base = (rt * 16 + 4 * g) * 40 + ht * 16 + c0;
        pst[base]       = (unsigned short)a01;
        pst[base + 40]  = (unsigned short)(a01 >> 16);
        pst[base + 80]  = (unsigned short)a23;
        pst[base + 120] = (unsigned short)(a23 >> 16);
      }

    bf16x8 ag0 = *(const bf16x8*)&pst[(c0) * 40 + 8 * g];
    bf16x8 ag1 = *(const bf16x8*)&pst[(16 + c0) * 40 + 8 * g];

#pragma unroll
    for (int ct = 0; ct < 4; ++ct) {
      const float bov = bo[ct * 16 + c0];
      f32x4 a; a[0] = bov; a[1] = bov; a[2] = bov; a[3] = bov;
      const float* m = wo + (8 * g) * Cc + ct * 16 + c0;
      frag_u cv;
#pragma unroll
      for (int p = 0; p < 4; ++p)
        cv.u[p] = cvt2(m[(2 * p) * Cc], m[(2 * p + 1) * Cc]);
      y[0][ct] = __builtin_amdgcn_mfma_f32_16x16x32_bf16(ag0, cv.v, a, 0, 0, 0);
      y[1][ct] = __builtin_amdgcn_mfma_f32_16x16x32_bf16(ag1, cv.v, a, 0, 0, 0);
    }
    // residual
#pragma unroll
    for (int rt = 0; rt < 2; ++rt)
#pragma unroll
      for (int ct = 0; ct < 4; ++ct)
#pragma unroll
        for (int r = 0; r < 4; ++r)
          y[rt][ct][r] += bf2f(xp[(R + rt * 16 + 4 * g + r) * 72 + ct * 16 + c0]);
  }

  // ---------------- Phase 6: LayerNorm over C, stage in LDS, contiguous bf16 store ----------------
  {
    float gam[4], bet[4];
#pragma unroll
    for (int ct = 0; ct < 4; ++ct) { gam[ct] = gamma[ct * 16 + c0]; bet[ct] = beta[ct * 16 + c0]; }

#pragma unroll
    for (int rt = 0; rt < 2; ++rt) {
#pragma unroll
      for (int r = 0; r < 4; ++r) {
        float sum = 0.f;
#pragma unroll
        for (int ct = 0; ct < 4; ++ct) sum += y[rt][ct][r];
        sum = redsum16(sum);
        const float mu = sum * (1.0f / 64.0f);
        float vs = 0.f;
#pragma unroll
        for (int ct = 0; ct < 4; ++ct) { const float d = y[rt][ct][r] - mu; vs += d * d; }
        vs = redsum16(vs);
        const float rs = rsqrtf(vs * (1.0f / 64.0f) + 1e-5f);
        const int row = R + rt * 16 + 4 * g + r;
#pragma unroll
        for (int ct = 0; ct < 2; ++ct) {
          const unsigned int p = cvt2((y[rt][2 * ct][r] - mu) * rs * gam[2 * ct] + bet[2 * ct],
                                      (y[rt][2 * ct + 1][r] - mu) * rs * gam[2 * ct + 1] + bet[2 * ct + 1]);
          // pair elements are 16 apart in c -> two b16 stores
          xp[row * 72 + (2 * ct) * 16 + c0]     = (unsigned short)p;
          xp[row * 72 + (2 * ct + 1) * 16 + c0] = (unsigned short)(p >> 16);
        }
      }
    }
  }

  __syncthreads();

  // contiguous bf16 tile store (in-place over this block's xt region)
  {
    const int r = tid >> 1;
    const int half = (tid & 1) * 32;
    bf16x8 v[4];
#pragma unroll
    for (int j = 0; j < 4; ++j) v[j] = *(const bf16x8*)&xp[r * 72 + half + 8 * j];
    unsigned short* dst = xtile + (size_t)r * Cc + half;
#pragma unroll
    for (int j = 0; j < 4; ++j) *(bf16x8*)(dst + 8 * j) = v[j];
  }
}

extern "C" void kernel_launch(void* const* d_in, const int* in_sizes, int n_in,
                              void* d_out, int out_size, void* d_ws, size_t ws_size,
                              hipStream_t stream) {
  const float* x = (const float*)d_in[0];
  float* out = (float*)d_out;
  unsigned short* xt = (unsigned short*)d_ws;   // 8*512*128*64 bf16 = 64 MB (proven footprint)

  sta_tin<<<dim3(Nn / 64, Tt, Bq), dim3(256), 0, stream>>>(x, xt);

  sta_core<<<dim3(Bq * Nn), dim3(256), 0, stream>>>(
      xt,
      (const float*)d_in[1], (const float*)d_in[2],
      (const float*)d_in[3], (const float*)d_in[4],
      (const float*)d_in[5], (const float*)d_in[6],
      (const float*)d_in[7], (const float*)d_in[8],
      (const float*)d_in[9], (const float*)d_in[10],
      (const float*)d_in[11], (const float*)d_in[12]);

  sta_tout<<<dim3(Nn / 64, Tt, Bq), dim3(256), 0, stream>>>(xt, out);
}

// Round 14
// 164.403 us; speedup vs baseline: 1.0877x; 1.0478x over previous
//
#include <hip/hip_runtime.h>

#define Bq 8
#define Cc 64
#define Tt 128
#define Nn 512
#define Hh 32

typedef __attribute__((ext_vector_type(8))) short bf16x8;
typedef __attribute__((ext_vector_type(4))) float f32x4;
typedef __attribute__((ext_vector_type(4))) unsigned int u32x4;

typedef union { unsigned int u[4]; bf16x8 v; } frag_u;

__device__ __forceinline__ unsigned short f2bf(float f) {
  union { float f; unsigned int i; } u; u.f = f;
  unsigned int r = (u.i + 0x7FFFu + ((u.i >> 16) & 1u)) >> 16;
  return (unsigned short)r;
}
__device__ __forceinline__ float bf2f(unsigned short h) {
  union { float f; unsigned int i; } u; u.i = ((unsigned int)h) << 16; return u.f;
}
// HW packed f32->bf16 (RNE): low16 = bf16(lo), high16 = bf16(hi)
__device__ __forceinline__ unsigned int cvt2(float lo, float hi) {
  unsigned int r;
  asm("v_cvt_pk_bf16_f32 %0, %1, %2" : "=v"(r) : "v"(lo), "v"(hi));
  return r;
}

// ---------------- Pass 1: x[B,C,T,N] f32 -> xt[B,N,T,C] bf16 (tiled transpose) ----------------
__global__ __launch_bounds__(256) void sta_tin(const float* __restrict__ x,
                                               unsigned short* __restrict__ xt) {
  __shared__ float tile[64][65];
  const int tid = threadIdx.x;
  const int nb = blockIdx.x, t = blockIdx.y, b = blockIdx.z;
  const int n0 = nb * 64;

#pragma unroll
  for (int i = 0; i < 4; ++i) {
    const int c = i * 16 + (tid >> 4);
    const int nf = (tid & 15) * 4;
    const float4 v = *(const float4*)(x + (((size_t)(b * Cc + c) * Tt + t) * Nn + n0 + nf));
    tile[c][nf + 0] = v.x; tile[c][nf + 1] = v.y; tile[c][nf + 2] = v.z; tile[c][nf + 3] = v.w;
  }
  __syncthreads();

  const int np = tid >> 2;
  const int cq = (tid & 3) * 16;
  unsigned int u[8];
#pragma unroll
  for (int k = 0; k < 8; ++k)
    u[k] = cvt2(tile[cq + 2 * k][np], tile[cq + 2 * k + 1][np]);
  unsigned short* dst = xt + (((size_t)(b * Nn + n0 + np) * Tt + t) * Cc + cq);
  u32x4 s0 = { u[0], u[1], u[2], u[3] };
  u32x4 s1 = { u[4], u[5], u[6], u[7] };
  *(u32x4*)(dst) = s0;
  *(u32x4*)(dst + 8) = s1;
}

// ---------------- Pass 3: yt[B,N,T,C] bf16 -> out[B,C,T,N] f32 (tiled transpose) ----------------
__global__ __launch_bounds__(256) void sta_tout(const unsigned short* __restrict__ yt,
                                                float* __restrict__ out) {
  __shared__ float tile[64][65];
  const int tid = threadIdx.x;
  const int nb = blockIdx.x, t = blockIdx.y, b = blockIdx.z;
  const int n0 = nb * 64;

  {
    const int np = tid >> 2;
    const int cq = (tid & 3) * 16;
    const unsigned short* src = yt + (((size_t)(b * Nn + n0 + np) * Tt + t) * Cc + cq);
    const bf16x8 v0 = *(const bf16x8*)(src);
    const bf16x8 v1 = *(const bf16x8*)(src + 8);
#pragma unroll
    for (int j = 0; j < 8; ++j) {
      tile[np][cq + j]     = bf2f((unsigned short)v0[j]);
      tile[np][cq + 8 + j] = bf2f((unsigned short)v1[j]);
    }
  }
  __syncthreads();

  const int c = tid >> 2;
  const int nq = (tid & 3) * 16;
#pragma unroll
  for (int k = 0; k < 4; ++k) {
    float4 w;
    w.x = tile[nq + 4 * k + 0][c];
    w.y = tile[nq + 4 * k + 1][c];
    w.z = tile[nq + 4 * k + 2][c];
    w.w = tile[nq + 4 * k + 3][c];
    *(float4*)(out + (((size_t)(b * Cc + c) * Tt + t) * Nn + n0 + nq + 4 * k)) = w;
  }
}

// ---------------- Pass 2: fused attention on contiguous bf16 tiles (in-place xt -> yt) ----------------
__global__ __launch_bounds__(256, 3) void sta_core(
    unsigned short* __restrict__ xt,
    const float* __restrict__ wq, const float* __restrict__ bq,
    const float* __restrict__ wk, const float* __restrict__ bk,
    const float* __restrict__ wv, const float* __restrict__ bv,
    const float* __restrict__ wg, const float* __restrict__ bg,
    const float* __restrict__ wo, const float* __restrict__ bo,
    const float* __restrict__ gamma, const float* __restrict__ beta)
{
  __shared__ __align__(16) unsigned short xp[Tt * 72];     // xp[t][c]   18,432 B
  __shared__ __align__(16) unsigned short ksm[Tt * 40];    // k[t][h]    10,240 B
  __shared__ __align__(16) unsigned short vT[Hh * 136];    // vT[h][s]    8,704 B
  __shared__ __align__(16) unsigned short stg[4 * 32 * 40];// per-wave   10,240 B
  __shared__ float pb[128];                                // posbias*log2e  512 B

  const int tid  = threadIdx.x;
  const int lane = tid & 63;
  const int w    = tid >> 6;
  const int g    = lane >> 4;
  const int c0   = lane & 15;
  const int R    = w * 32;

  unsigned short* xtile = xt + (size_t)blockIdx.x * (Tt * Cc);

  // ---------------- Phase 0: contiguous 16KB tile -> LDS ----------------
  {
    const int r = tid >> 1;
    const int half = (tid & 1) * 32;
    const unsigned short* src = xtile + (size_t)r * Cc + half;
    bf16x8 v[4];
#pragma unroll
    for (int j = 0; j < 4; ++j) v[j] = *(const bf16x8*)(src + 8 * j);
#pragma unroll
    for (int j = 0; j < 4; ++j) *(bf16x8*)&xp[r * 72 + half + 8 * j] = v[j];
  }

  // position-bias table: pb[d] = exp(-d/128) * log2(e)  (additive exponent, exp2 domain)
  if (tid < 128) pb[tid] = exp2f((float)tid * -0.0112710550069f) * 1.4426950408889634f;

  // QKV weight B-fragments, built in-kernel exactly where R6 builds them (frozen structure).
  bf16x8 bwf[3][2][2];      // [q/k/v][ct][kstep]
  float  bias0[3][2];
  {
    const float* ws3[3] = { wq, wk, wv };
    const float* bs3[3] = { bq, bk, bv };
#pragma unroll
    for (int o = 0; o < 3; ++o) {
#pragma unroll
      for (int ct = 0; ct < 2; ++ct) {
        bias0[o][ct] = bs3[o][ct * 16 + c0];
#pragma unroll
        for (int ks2 = 0; ks2 < 2; ++ks2) {
          const float* m = ws3[o] + (ks2 * 32 + 8 * g) * Hh + ct * 16 + c0;
          frag_u cv;
#pragma unroll
          for (int p = 0; p < 4; ++p)
            cv.u[p] = cvt2(m[(2 * p) * Hh], m[(2 * p + 1) * Hh]);
          bwf[o][ct][ks2] = cv.v;
        }
      }
    }
  }

  __syncthreads();

  // ---------------- Phase 1: QKV = xp @ {wq,wk,wv} + bias ----------------
  unsigned short* pst = &stg[w * 1280];
  {
    f32x4 acc[3][2][2];
#pragma unroll
    for (int o = 0; o < 3; ++o)
#pragma unroll
      for (int rt = 0; rt < 2; ++rt)
#pragma unroll
        for (int ct = 0; ct < 2; ++ct) {
          f32x4 a; a[0] = bias0[o][ct]; a[1] = bias0[o][ct]; a[2] = bias0[o][ct]; a[3] = bias0[o][ct];
          acc[o][rt][ct] = a;
        }
    bf16x8 af[2][2];
#pragma unroll
    for (int rt = 0; rt < 2; ++rt)
#pragma unroll
      for (int ks2 = 0; ks2 < 2; ++ks2)
        af[rt][ks2] = *(const bf16x8*)&xp[(R + rt * 16 + c0) * 72 + ks2 * 32 + 8 * g];
#pragma unroll
    for (int o = 0; o < 3; ++o)
#pragma unroll
      for (int rt = 0; rt < 2; ++rt)
#pragma unroll
        for (int ct = 0; ct < 2; ++ct)
#pragma unroll
          for (int ks2 = 0; ks2 < 2; ++ks2)
            acc[o][rt][ct] = __builtin_amdgcn_mfma_f32_16x16x32_bf16(af[rt][ks2], bwf[o][ct][ks2], acc[o][rt][ct], 0, 0, 0);

    // scatter D-frags via packed cvt: q -> pst, k -> ksm, v -> vT (transposed)
#pragma unroll
    for (int rt = 0; rt < 2; ++rt)
#pragma unroll
      for (int ct = 0; ct < 2; ++ct) {
        const unsigned int q01 = cvt2(acc[0][rt][ct][0], acc[0][rt][ct][1]);
        const unsigned int q23 = cvt2(acc[0][rt][ct][2], acc[0][rt][ct][3]);
        const unsigned int k01 = cvt2(acc[1][rt][ct][0], acc[1][rt][ct][1]);
        const unsigned int k23 = cvt2(acc[1][rt][ct][2], acc[1][rt][ct][3]);
        const int qb = (rt * 16 + 4 * g) * 40 + ct * 16 + c0;
        pst[qb]       = (unsigned short)q01;
        pst[qb + 40]  = (unsigned short)(q01 >> 16);
        pst[qb + 80]  = (unsigned short)q23;
        pst[qb + 120] = (unsigned short)(q23 >> 16);
        const int kb = (R + rt * 16 + 4 * g) * 40 + ct * 16 + c0;
        ksm[kb]       = (unsigned short)k01;
        ksm[kb + 40]  = (unsigned short)(k01 >> 16);
        ksm[kb + 80]  = (unsigned short)k23;
        ksm[kb + 120] = (unsigned short)(k23 >> 16);
        const unsigned int p0 = cvt2(acc[2][rt][ct][0], acc[2][rt][ct][1]);
        const unsigned int p1 = cvt2(acc[2][rt][ct][2], acc[2][rt][ct][3]);
        unsigned int* vd = (unsigned int*)&vT[(ct * 16 + c0) * 136 + R + rt * 16 + 4 * g];
        vd[0] = p0; vd[1] = p1;
      }
  }

  __syncthreads();

  // ---------------- Phase 2: S^T = K.Q^T (swapped operands), lane-local softmax ----------------
  // D-frag of S^T: lane (g,c0) reg r holds S[q = R + rt*16 + c0][s = ct*16 + 4*g + r].
  f32x4 s[2][8];
  {
    const f32x4 zero = { 0.f, 0.f, 0.f, 0.f };
    bf16x8 aq[2];
    aq[0] = *(const bf16x8*)&pst[(c0) * 40 + 8 * g];
    aq[1] = *(const bf16x8*)&pst[(16 + c0) * 40 + 8 * g];
#pragma unroll
    for (int ct = 0; ct < 8; ++ct) {
      bf16x8 bkf = *(const bf16x8*)&ksm[(ct * 16 + c0) * 40 + 8 * g];
      s[0][ct] = __builtin_amdgcn_mfma_f32_16x16x32_bf16(bkf, aq[0], zero, 0, 0, 0);
      s[1][ct] = __builtin_amdgcn_mfma_f32_16x16x32_bf16(bkf, aq[1], zero, 0, 0, 0);
    }
  }

  float rl[2];
#pragma unroll
  for (int rt = 0; rt < 2; ++rt) {
    const int tq = R + rt * 16 + c0;      // this lane's q row (fixed)
    float sum = 0.f;
#pragma unroll
    for (int ct = 0; ct < 8; ++ct) {
      const int sb = ct * 16 + 4 * g;
#pragma unroll
      for (int r = 0; r < 4; ++r) {
        const int d = tq - (sb + r);
        const int ad = d < 0 ? -d : d;
        const float e = exp2f(s[rt][ct][r] * (0.17677669529663687f * 1.4426950408889634f) + pb[ad]);
        s[rt][ct][r] = e;
        sum += e;
      }
    }
    sum += __shfl_xor(sum, 16, 64);       // sum across the 4 g-groups (same c0)
    sum += __shfl_xor(sum, 32, 64);
    rl[rt] = 1.0f / sum;
  }

  // ---------------- Phase 3: out = P @ v; P staged [q=c0][s] via b64 (rl pre-folded) ----------------
  f32x4 o[2][2];
  {
    const f32x4 zero = { 0.f, 0.f, 0.f, 0.f };
    o[0][0] = zero; o[0][1] = zero; o[1][0] = zero; o[1][1] = zero;
#pragma unroll
    for (int ss = 0; ss < 4; ++ss) {
#pragma unroll
      for (int rt = 0; rt < 2; ++rt)
#pragma unroll
        for (int lct = 0; lct < 2; ++lct) {
          const int ct = ss * 2 + lct;
          const unsigned int a01 = cvt2(s[rt][ct][0] * rl[rt], s[rt][ct][1] * rl[rt]);
          const unsigned int a23 = cvt2(s[rt][ct][2] * rl[rt], s[rt][ct][3] * rl[rt]);
          // P[q = c0][s_local = lct*16 + 4g + r]: 4 consecutive shorts -> one b64
          unsigned int* pd = (unsigned int*)&pst[rt * 640 + c0 * 40 + lct * 16 + 4 * g];
          pd[0] = a01; pd[1] = a23;
        }
      bf16x8 ap0 = *(const bf16x8*)&pst[c0 * 40 + 8 * g];
      bf16x8 ap1 = *(const bf16x8*)&pst[640 + c0 * 40 + 8 * g];
#pragma unroll
      for (int ht = 0; ht < 2; ++ht) {
        bf16x8 bv2 = *(const bf16x8*)&vT[(ht * 16 + c0) * 136 + ss * 32 + 8 * g];
        o[0][ht] = __builtin_amdgcn_mfma_f32_16x16x32_bf16(ap0, bv2, o[0][ht], 0, 0, 0);
        o[1][ht] = __builtin_amdgcn_mfma_f32_16x16x32_bf16(ap1, bv2, o[1][ht], 0, 0, 0);
      }
    }
    // rl already folded into P; o D-frag layout: row q = R+rt*16+4g+r, col h = ht*16+c0
  }

  // ---------------- Phase 4: temporal gate ----------------
  bf16x8 ag0, ag1;   // gated O in [q][h] fragment layout, reused by Phase 5
  {
#pragma unroll
    for (int rt = 0; rt < 2; ++rt)
#pragma unroll
      for (int ht = 0; ht < 2; ++ht) {
        const unsigned int a01 = cvt2(o[rt][ht][0], o[rt][ht][1]);
        const unsigned int a23 = cvt2(o[rt][ht][2], o[rt][ht][3]);
        const int base = (rt * 16 + 4 * g) * 40 + ht * 16 + c0;
        pst[base]       = (unsigned short)a01;
        pst[base + 40]  = (unsigned short)(a01 >> 16);
        pst[base + 80]  = (unsigned short)a23;
        pst[base + 120] = (unsigned short)(a23 >> 16);
      }

    bf16x8 ao0 = *(const bf16x8*)&pst[(c0) * 40 + 8 * g];
    bf16x8 ao1 = *(const bf16x8*)&pst[(16 + c0) * 40 + 8 * g];

    f32x4 gt[2][2];
#pragma unroll
    for (int ct = 0; ct < 2; ++ct) {
      const float bgv = bg[ct * 16 + c0];
      f32x4 a; a[0] = bgv; a[1] = bgv; a[2] = bgv; a[3] = bgv;
      const float* m = wg + (8 * g) * Hh + ct * 16 + c0;
      frag_u cv;
#pragma unroll
      for (int p = 0; p < 4; ++p)
        cv.u[p] = cvt2(m[(2 * p) * Hh], m[(2 * p + 1) * Hh]);
      gt[0][ct] = __builtin_amdgcn_mfma_f32_16x16x32_bf16(ao0, cv.v, a, 0, 0, 0);
      gt[1][ct] = __builtin_amdgcn_mfma_f32_16x16x32_bf16(ao1, cv.v, a, 0, 0, 0);
    }
#pragma unroll
    for (int rt = 0; rt < 2; ++rt)
#pragma unroll
      for (int ct = 0; ct < 2; ++ct)
#pragma unroll
        for (int r = 0; r < 4; ++r) {
          const float sg = 1.0f / (1.0f + exp2f(gt[rt][ct][r] * -1.4426950408889634f));
          o[rt][ct][r] *= sg;
        }

    // stage gated o -> pst, read back as [q][h] fragments for Phase 5's B operand
#pragma unroll
    for (int rt = 0; rt < 2; ++rt)
#pragma unroll
      for (int ht = 0; ht < 2; ++ht) {
        const unsigned int a01 = cvt2(o[rt][ht][0], o[rt][ht][1]);
        const unsigned int a23 = cvt2(o[rt][ht][2], o[rt][ht][3]);
        const int base = (rt * 16 + 4 * g) * 40 + ht * 16 + c0;
        pst[base]       = (unsigned short)a01;
        pst[base + 40]  = (unsigned short)(a01 >> 16);
        pst[base + 80]  = (unsigned short)a23;
        pst[base + 120] = (unsigned short)(a23 >> 16);
      }
    ag0 = *(const bf16x8*)&pst[(c0) * 40 + 8 * g];
    ag1 = *(const bf16x8*)&pst[(16 + c0) * 40 + 8 * g];
  }

  // ---------------- Phase 5: y^T = wo^T @ gated^T + bo (transposed output) ----------------
  // A = wo^T fragment (IDENTICAL gather to the old wo frag); B = ag (identical read).
  // D-frag: lane (g,c0) reg r holds y[c = cb*16 + 4g + r][q = R + rt*16 + c0].
  f32x4 yT[2][4];   // [rt][cb]
  {
#pragma unroll
    for (int cb = 0; cb < 4; ++cb) {
      const float4 bo4 = *(const float4*)(bo + cb * 16 + 4 * g);
      f32x4 a; a[0] = bo4.x; a[1] = bo4.y; a[2] = bo4.z; a[3] = bo4.w;
      const float* m = wo + (8 * g) * Cc + cb * 16 + c0;
      frag_u cv;
#pragma unroll
      for (int p = 0; p < 4; ++p)
        cv.u[p] = cvt2(m[(2 * p) * Cc], m[(2 * p + 1) * Cc]);
      yT[0][cb] = __builtin_amdgcn_mfma_f32_16x16x32_bf16(cv.v, ag0, a, 0, 0, 0);
      yT[1][cb] = __builtin_amdgcn_mfma_f32_16x16x32_bf16(cv.v, ag1, a, 0, 0, 0);
    }
    // residual: y^T[c][q] += x[q][c]; 4 consecutive c -> one b64 LDS read
#pragma unroll
    for (int rt = 0; rt < 2; ++rt) {
      const int q = R + rt * 16 + c0;
#pragma unroll
      for (int cb = 0; cb < 4; ++cb) {
        const unsigned int* rp = (const unsigned int*)&xp[q * 72 + cb * 16 + 4 * g];
        const unsigned int r0 = rp[0], r1 = rp[1];
        yT[rt][cb][0] += bf2f((unsigned short)r0);
        yT[rt][cb][1] += bf2f((unsigned short)(r0 >> 16));
        yT[rt][cb][2] += bf2f((unsigned short)r1);
        yT[rt][cb][3] += bf2f((unsigned short)(r1 >> 16));
      }
    }
  }

  // ---------------- Phase 6: LayerNorm over C (lane-local + 2 shuffles), b64 stores ----------------
  {
#pragma unroll
    for (int rt = 0; rt < 2; ++rt) {
      float sum = 0.f;
#pragma unroll
      for (int cb = 0; cb < 4; ++cb)
#pragma unroll
        for (int r = 0; r < 4; ++r) sum += yT[rt][cb][r];
      sum += __shfl_xor(sum, 16, 64);
      sum += __shfl_xor(sum, 32, 64);
      const float mu = sum * (1.0f / 64.0f);
      float vs = 0.f;
#pragma unroll
      for (int cb = 0; cb < 4; ++cb)
#pragma unroll
        for (int r = 0; r < 4; ++r) { const float d = yT[rt][cb][r] - mu; vs += d * d; }
      vs += __shfl_xor(vs, 16, 64);
      vs += __shfl_xor(vs, 32, 64);
      const float rs = rsqrtf(vs * (1.0f / 64.0f) + 1e-5f);
      const int q = R + rt * 16 + c0;
#pragma unroll
      for (int cb = 0; cb < 4; ++cb) {
        const float4 ga = *(const float4*)(gamma + cb * 16 + 4 * g);
        const float4 be = *(const float4*)(beta + cb * 16 + 4 * g);
        const unsigned int a01 = cvt2((yT[rt][cb][0] - mu) * rs * ga.x + be.x,
                                      (yT[rt][cb][1] - mu) * rs * ga.y + be.y);
        const unsigned int a23 = cvt2((yT[rt][cb][2] - mu) * rs * ga.z + be.z,
                                      (yT[rt][cb][3] - mu) * rs * ga.w + be.w);
        unsigned int* wp = (unsigned int*)&xp[q * 72 + cb * 16 + 4 * g];
        wp[0] = a01; wp[1] = a23;
      }
    }
  }

  __syncthreads();

  // contiguous bf16 tile store (in-place over this block's xt region)
  {
    const int r = tid >> 1;
    const int half = (tid & 1) * 32;
    bf16x8 v[4];
#pragma unroll
    for (int j = 0; j < 4; ++j) v[j] = *(const bf16x8*)&xp[r * 72 + half + 8 * j];
    unsigned short* dst = xtile + (size_t)r * Cc + half;
#pragma unroll
    for (int j = 0; j < 4; ++j) *(bf16x8*)(dst + 8 * j) = v[j];
  }
}

extern "C" void kernel_launch(void* const* d_in, const int* in_sizes, int n_in,
                              void* d_out, int out_size, void* d_ws, size_t ws_size,
                              hipStream_t stream) {
  const float* x = (const float*)d_in[0];
  float* out = (float*)d_out;
  unsigned short* xt = (unsigned short*)d_ws;   // 8*512*128*64 bf16 = 64 MB (proven footprint)

  sta_tin<<<dim3(Nn / 64, Tt, Bq), dim3(256), 0, stream>>>(x, xt);

  sta_core<<<dim3(Bq * Nn), dim3(256), 0, stream>>>(
      xt,
      (const float*)d_in[1], (const float*)d_in[2],
      (const float*)d_in[3], (const float*)d_in[4],
      (const float*)d_in[5], (const float*)d_in[6],
      (const float*)d_in[7], (const float*)d_in[8],
      (const float*)d_in[9], (const float*)d_in[10],
      (const float*)d_in[11], (const float*)d_in[12]);

  sta_tout<<<dim3(Nn / 64, Tt, Bq), dim3(256), 0, stream>>>(xt, out);
}